// Round 1
// baseline (484.319 us; speedup 1.0000x reference)
//
#include <hip/hip_runtime.h>
#include <math.h>

// Problem constants (B=4, N=1024, C=1024, H=16, hd=64)
#define B_  4
#define N_  1024
#define C_  1024
#define H_  16
#define HD  64
#define M_  (B_ * N_)   // 4096 rows
#define K3  (3 * C_)    // 3072 qkv cols
#define BH  (B_ * H_)   // 64

typedef _Float16 half8 __attribute__((ext_vector_type(8)));
typedef _Float16 half4 __attribute__((ext_vector_type(4)));
typedef float floatx4 __attribute__((ext_vector_type(4)));

// Async global->LDS, 16B per lane. LDS dst must be wave-uniform base + lane*16.
__device__ inline void gload16(const void* g, void* l) {
    __builtin_amdgcn_global_load_lds((const __attribute__((address_space(1))) void*)g,
                                     (__attribute__((address_space(3))) void*)l,
                                     16, 0, 0);
}

// ---------------------------------------------------------------------------
// qkv GEMM with FUSED rmsnorm epilogue (verified round 6). UNCHANGED.
// ---------------------------------------------------------------------------
__global__ __launch_bounds__(256) void gemm_qkv(const _Float16* __restrict__ A,
                                                const _Float16* __restrict__ Bt,
                                                const float* __restrict__ bqkv,
                                                const float* __restrict__ q_scale,
                                                const float* __restrict__ k_scale,
                                                _Float16* __restrict__ qh,
                                                _Float16* __restrict__ kh,
                                                _Float16* __restrict__ vh) {
    __shared__ _Float16 As[128 * 32];
    __shared__ _Float16 Bs[128 * 32];
    const int tid = threadIdx.x;
    const int lane = tid & 63;
    const int wave = tid >> 6;
    const int wm = (wave & 1) * 64, wn = (wave >> 1) * 64;
    const int quad = lane >> 4, l16 = lane & 15;
    const int bm = blockIdx.y * 128, bn = blockIdx.x * 128;
    const int K = C_;

    const int idx0 = tid, idx1 = tid + 256;
    const int r0 = idx0 >> 2, c0 = idx0 & 3, g0 = (c0 - (r0 >> 1)) & 3;
    const int r1 = idx1 >> 2, c1 = idx1 & 3, g1 = (c1 - (r1 >> 1)) & 3;
    const _Float16* Ar0 = A + (size_t)(bm + r0) * K + g0 * 8;
    const _Float16* Ar1 = A + (size_t)(bm + r1) * K + g1 * 8;
    const _Float16* Br0 = Bt + (size_t)(bn + r0) * K + g0 * 8;
    const _Float16* Br1 = Bt + (size_t)(bn + r1) * K + g1 * 8;
    _Float16* lA0 = As + (size_t)(idx0 & ~63) * 8;
    _Float16* lA1 = As + (size_t)(idx1 & ~63) * 8;
    _Float16* lB0 = Bs + (size_t)(idx0 & ~63) * 8;
    _Float16* lB1 = Bs + (size_t)(idx1 & ~63) * 8;

    floatx4 acc[4][4] = {};

    for (int k0 = 0; k0 < K; k0 += 32) {
        gload16(Ar0 + k0, lA0);
        gload16(Ar1 + k0, lA1);
        gload16(Br0 + k0, lB0);
        gload16(Br1 + k0, lB1);
        __syncthreads();

        half8 af[4], bf[4];
#pragma unroll
        for (int i = 0; i < 4; ++i) {
            int m = wm + i * 16 + l16;
            int rot = (quad + (m >> 1)) & 3;
            af[i] = *(const half8*)(As + m * 32 + rot * 8);
            int n = wn + i * 16 + l16;
            int rotb = (quad + (n >> 1)) & 3;
            bf[i] = *(const half8*)(Bs + n * 32 + rotb * 8);
        }
#pragma unroll
        for (int i = 0; i < 4; ++i)
#pragma unroll
            for (int j = 0; j < 4; ++j)
                acc[i][j] = __builtin_amdgcn_mfma_f32_16x16x32_f16(af[i], bf[j], acc[i][j], 0, 0, 0);
        __syncthreads();
    }

    // ---- fused epilogue ----
    const int hh = (bn + wn) >> 6;          // head-slice 0..47
    const int which = hh >> 4, h = hh & 15; // 0=q, 1=k, 2=v
    _Float16* outp = (which == 0) ? qh : ((which == 1) ? kh : vh);

    float bvv[4], scl[4];
#pragma unroll
    for (int j = 0; j < 4; ++j) bvv[j] = bqkv[bn + wn + j * 16 + l16];
    if (which < 2) {
        const float* sv = which ? k_scale : q_scale;
#pragma unroll
        for (int j = 0; j < 4; ++j) scl[j] = sv[j * 16 + l16];
    }

#pragma unroll
    for (int i = 0; i < 4; ++i) {
#pragma unroll
        for (int r = 0; r < 4; ++r) {
            float v4[4], ss = 0.f;
#pragma unroll
            for (int j = 0; j < 4; ++j) {
                float v = acc[i][j][r] + bvv[j];
                v4[j] = v;
                ss += v * v;
            }
            int grow = bm + wm + i * 16 + quad * 4 + r;
            int b = grow >> 10, n = grow & 1023;
            _Float16* dst = outp + (((size_t)(b * H_ + h) * N_ + n) << 6);
            if (which < 2) {
#pragma unroll
                for (int off = 1; off < 16; off <<= 1) ss += __shfl_xor(ss, off, 64);
                float inv = 1.0f / (sqrtf(ss * (1.0f / 64.0f)) + 1e-8f);
#pragma unroll
                for (int j = 0; j < 4; ++j) dst[j * 16 + l16] = (_Float16)(v4[j] * scl[j] * inv);
            } else {
#pragma unroll
                for (int j = 0; j < 4; ++j) dst[j * 16 + l16] = (_Float16)v4[j];
            }
        }
    }
}

// ---------------------------------------------------------------------------
// proj GEMM, 128x64 tiles: Cout[4096 x 1024] = A @ Bt^T + bias (fp32 out).
// ROUND 7: old 128x128 launch was 256 blocks = 1 block/CU = 1 wave/SIMD, so
// every barrier drain was fully exposed. 128x64 -> 512 blocks = 2 blocks/CU
// gives cross-block overlap. Same verified MFMA/swizzle structure, acc[4][2].
// ---------------------------------------------------------------------------
__global__ __launch_bounds__(256) void gemm_proj(const _Float16* __restrict__ A,
                                                 const _Float16* __restrict__ Bt,
                                                 const float* __restrict__ bias,
                                                 float* __restrict__ Cout) {
    __shared__ _Float16 As[128 * 32];
    __shared__ _Float16 Bs[64 * 32];
    const int tid = threadIdx.x;
    const int lane = tid & 63;
    const int wave = tid >> 6;
    const int wm = (wave & 1) * 64, wn = (wave >> 1) * 32;
    const int quad = lane >> 4, l16 = lane & 15;
    const int bm = blockIdx.y * 128, bn = blockIdx.x * 64;
    const int K = C_;

    const int idx0 = tid, idx1 = tid + 256;
    const int r0 = idx0 >> 2, c0 = idx0 & 3, g0 = (c0 - (r0 >> 1)) & 3;
    const int r1 = idx1 >> 2, c1 = idx1 & 3, g1 = (c1 - (r1 >> 1)) & 3;
    const _Float16* Ar0 = A + (size_t)(bm + r0) * K + g0 * 8;
    const _Float16* Ar1 = A + (size_t)(bm + r1) * K + g1 * 8;
    const _Float16* Br0 = Bt + (size_t)(bn + r0) * K + g0 * 8;  // r0 in 0..63
    _Float16* lA0 = As + (size_t)(idx0 & ~63) * 8;
    _Float16* lA1 = As + (size_t)(idx1 & ~63) * 8;
    _Float16* lB0 = Bs + (size_t)(idx0 & ~63) * 8;

    floatx4 acc[4][2] = {};

    for (int k0 = 0; k0 < K; k0 += 32) {
        gload16(Ar0 + k0, lA0);
        gload16(Ar1 + k0, lA1);
        gload16(Br0 + k0, lB0);
        __syncthreads();

        half8 af[4], bf[2];
#pragma unroll
        for (int i = 0; i < 4; ++i) {
            int m = wm + i * 16 + l16;
            int rot = (quad + (m >> 1)) & 3;
            af[i] = *(const half8*)(As + m * 32 + rot * 8);
        }
#pragma unroll
        for (int j = 0; j < 2; ++j) {
            int n = wn + j * 16 + l16;
            int rotb = (quad + (n >> 1)) & 3;
            bf[j] = *(const half8*)(Bs + n * 32 + rotb * 8);
        }
#pragma unroll
        for (int i = 0; i < 4; ++i)
#pragma unroll
            for (int j = 0; j < 2; ++j)
                acc[i][j] = __builtin_amdgcn_mfma_f32_16x16x32_f16(af[i], bf[j], acc[i][j], 0, 0, 0);
        __syncthreads();
    }

#pragma unroll
    for (int i = 0; i < 4; ++i) {
        int grow = bm + wm + i * 16 + quad * 4;
#pragma unroll
        for (int j = 0; j < 2; ++j) {
            int gcol = bn + wn + j * 16 + l16;
            float bv = bias[gcol];
#pragma unroll
            for (int r = 0; r < 4; ++r)
                Cout[(size_t)(grow + r) * C_ + gcol] = acc[i][j][r] + bv;
        }
    }
}

// ---------------------------------------------------------------------------
// Fused preprocessing: cast_half(x) + transpose_cast(W_qkv) + transpose_cast
// (W_proj) in ONE launch (5120 blocks). The three are independent; as three
// graph nodes they serialized, now they co-schedule.
// ---------------------------------------------------------------------------
__device__ inline void tcast_tile(const float* __restrict__ W, _Float16* __restrict__ Wt,
                                  int K, int N, int bk, int bn, int tid,
                                  _Float16 (*t)[65]) {
#pragma unroll
    for (int u = 0; u < 16; ++u) {
        int idx = u * 256 + tid;
        int r = idx >> 6, c = idx & 63;
        t[r][c] = (_Float16)W[(size_t)(bk + r) * N + bn + c];
    }
    __syncthreads();
#pragma unroll
    for (int u = 0; u < 16; ++u) {
        int idx = u * 256 + tid;
        int r = idx >> 6, c = idx & 63;
        Wt[(size_t)(bn + r) * K + bk + c] = t[c][r];
    }
}

__global__ __launch_bounds__(256) void prep(const float* __restrict__ x,
                                            _Float16* __restrict__ xh,
                                            const float* __restrict__ Wqkv,
                                            _Float16* __restrict__ Wqkvt,
                                            const float* __restrict__ Wproj,
                                            _Float16* __restrict__ Wprojt) {
    __shared__ _Float16 t[64][65];
    const int tid = threadIdx.x;
    const int bid = blockIdx.x;
    if (bid < 4096) {
        // cast x -> fp16, 4 elems/thread
        int i = bid * 256 + tid;
        float4 v = ((const float4*)x)[i];
        half4 o = { (_Float16)v.x, (_Float16)v.y, (_Float16)v.z, (_Float16)v.w };
        ((half4*)xh)[i] = o;
    } else if (bid < 4096 + 768) {
        // W_qkv [1024 x 3072] -> Wqkvt [3072 x 1024]; old grid dim3(48, 16)
        int bb = bid - 4096;
        int bn = (bb % 48) * 64, bk = (bb / 48) * 64;
        tcast_tile(Wqkv, Wqkvt, C_, K3, bk, bn, tid, t);
    } else {
        // W_proj [1024 x 1024] -> Wprojt [1024 x 1024]; old grid dim3(16, 16)
        int bb = bid - 4864;
        int bn = (bb % 16) * 64, bk = (bb / 16) * 64;
        tcast_tile(Wproj, Wprojt, C_, C_, bk, bn, tid, t);
    }
}

// ---------------------------------------------------------------------------
// vh fp16 [bh][n][64] -> vth fp16 [bh][d][n] (per-head transpose). UNCHANGED.
// ---------------------------------------------------------------------------
__global__ __launch_bounds__(256) void v_transpose_h(const _Float16* __restrict__ vh,
                                                     _Float16* __restrict__ vth) {
    __shared__ _Float16 t[64][65];
    const int tid = threadIdx.x;
    const int bh = blockIdx.y;
    const int j0 = blockIdx.x * 64;
#pragma unroll
    for (int u = 0; u < 16; ++u) {
        int idx = u * 256 + tid;
        int r = idx >> 6, c = idx & 63;
        t[r][c] = vh[((size_t)bh * N_ + j0 + r) * HD + c];
    }
    __syncthreads();
#pragma unroll
    for (int u = 0; u < 16; ++u) {
        int idx = u * 256 + tid;
        int d = idx >> 6, jj = idx & 63;
        vth[(size_t)bh * HD * N_ + (size_t)d * N_ + j0 + jj] = t[jj][d];
    }
}

// ---------------------------------------------------------------------------
// Fused flash attention v4. ROUND 7 changes vs verified round-6 v3:
//  * 128 q-rows/block, 512 threads (8 waves). Same 16 waves/CU occupancy and
//    same 128-VGPR cap as (256,4), but: half the resident blocks -> 512
//    concurrent bias streams instead of 1024 (HBM row locality), half the
//    K/V global->LDS staging traffic (each K/V tile serves 128 rows), half
//    the barrier events, 2 gload16/thread instead of 4.
//  * s_setprio(1) around both MFMA clusters (T5; attn-proven +4-7%).
// Per-wave math/layout identical to the verified version; staging index map
// (idx 0..511) is the union of the old idx0/idx1 paths -> same LDS bytes.
// ---------------------------------------------------------------------------
__global__ __launch_bounds__(512, 4) void flash_attn(const _Float16* __restrict__ qh,
                                                     const _Float16* __restrict__ kh,
                                                     const _Float16* __restrict__ vth,
                                                     const float* __restrict__ bias,
                                                     _Float16* __restrict__ attn_h) {
    __shared__ _Float16 Ks[2][64 * 64];   // [j][d], chunk c holds g = c^(row&7)
    __shared__ _Float16 Vs[2][64 * 64];   // [d][j], same swizzle
    __shared__ _Float16 Ps[8][16 * 64];   // per-wave P, same swizzle
    const int tid = threadIdx.x;
    const int lane = tid & 63, wave = tid >> 6;   // wave 0..7
    const int quad = lane >> 4, l16 = lane & 15;
    const int bh = blockIdx.y, b = bh >> 4, h = bh & 15;
    const int i0 = blockIdx.x * 128;

    const _Float16* qb = qh + (size_t)bh * N_ * HD;
    const _Float16* kb = kh + (size_t)bh * N_ * HD;
    const _Float16* vb = vth + (size_t)bh * HD * N_;
    const float* biasb = bias + (size_t)bh * N_ * N_ + (size_t)(i0 + wave * 16 + quad * 4) * N_ + l16;

    const int irow = i0 + wave * 16 + l16;
    half8 qf[2];
    qf[0] = *(const half8*)(qb + (size_t)irow * HD + quad * 8);
    qf[1] = *(const half8*)(qb + (size_t)irow * HD + 32 + quad * 8);

    const int idx0 = tid;                               // 0..511
    const int sr0 = idx0 >> 3, sg0 = (idx0 & 7) ^ (sr0 & 7);
    const _Float16* kg0 = kb + (size_t)sr0 * HD + sg0 * 8;
    const _Float16* vg0 = vb + (size_t)sr0 * N_ + sg0 * 8;
    const int ldsoff0 = (idx0 & ~63) * 8;

    floatx4 o_acc[4] = {};
    float l_lane[4] = {0.f, 0.f, 0.f, 0.f};
    float bvc[4][4], bvn[4][4];
    _Float16* Pw = Ps[wave];

    // prologue: stage tile 0 into buf 0; preload tile-0 bias
    gload16(kg0, Ks[0] + ldsoff0);
    gload16(vg0, Vs[0] + ldsoff0);
#pragma unroll
    for (int r = 0; r < 4; ++r)
#pragma unroll
        for (int s = 0; s < 4; ++s)
            bvc[r][s] = biasb[(size_t)r * N_ + s * 16];

    for (int t = 0; t < 16; ++t) {
        __syncthreads();   // drains stage(t) [vmcnt] and compute(t-1) LDS reads
        const _Float16* Kb = Ks[t & 1];
        const _Float16* Vb = Vs[t & 1];
        if (t < 15) {      // stage t+1 + prefetch its bias; in flight through compute(t)
            int j1 = (t + 1) * 64;
            gload16(kg0 + (size_t)j1 * HD, Ks[(t + 1) & 1] + ldsoff0);
            gload16(vg0 + j1, Vs[(t + 1) & 1] + ldsoff0);
#pragma unroll
            for (int r = 0; r < 4; ++r)
#pragma unroll
                for (int s = 0; s < 4; ++s)
                    bvn[r][s] = biasb[(size_t)r * N_ + j1 + s * 16];
        }

        // S = Q K^T for wave's 16 rows x 64 cols
        floatx4 sa[4] = {};
        __builtin_amdgcn_s_setprio(1);
#pragma unroll
        for (int kc = 0; kc < 2; ++kc) {
#pragma unroll
            for (int s = 0; s < 4; ++s) {
                int m = s * 16 + l16;
                half8 kf = *(const half8*)(Kb + m * 64 + (((kc * 4 + quad) ^ (l16 & 7)) * 8));
                sa[s] = __builtin_amdgcn_mfma_f32_16x16x32_f16(qf[kc], kf, sa[s], 0, 0, 0);
            }
        }
        __builtin_amdgcn_s_setprio(0);

        // fixed-offset softmax numerator: p = exp(0.125*s + bias - 6)
#pragma unroll
        for (int s = 0; s < 4; ++s) {
#pragma unroll
            for (int r = 0; r < 4; ++r) {
                float p = __expf(fmaf(sa[s][r], 0.125f, bvc[r][s]) - 6.0f);
                l_lane[r] += p;
                int i = quad * 4 + r;
                int cg = 2 * s + (l16 >> 3);
                Pw[i * 64 + ((cg ^ (i & 7)) * 8) + (l16 & 7)] = (_Float16)p;
            }
        }

        // wave-local LDS drain (Ps is per-wave; no block barrier needed)
        asm volatile("s_waitcnt lgkmcnt(0)" ::: "memory");

        // O += P @ V^T
        __builtin_amdgcn_s_setprio(1);
#pragma unroll
        for (int kc = 0; kc < 2; ++kc) {
            half8 pf = *(const half8*)(Pw + l16 * 64 + (((kc * 4 + quad) ^ (l16 & 7)) * 8));
#pragma unroll
            for (int s = 0; s < 4; ++s) {
                int n = s * 16 + l16;
                half8 vf = *(const half8*)(Vb + n * 64 + (((kc * 4 + quad) ^ (l16 & 7)) * 8));
                o_acc[s] = __builtin_amdgcn_mfma_f32_16x16x32_f16(pf, vf, o_acc[s], 0, 0, 0);
            }
        }
        __builtin_amdgcn_s_setprio(0);

        // rotate bias registers (renamed away by unroll)
#pragma unroll
        for (int r = 0; r < 4; ++r)
#pragma unroll
            for (int s = 0; s < 4; ++s)
                bvc[r][s] = bvn[r][s];
    }

    // epilogue: reduce row sums, normalize, store
#pragma unroll
    for (int r = 0; r < 4; ++r) {
#pragma unroll
        for (int off = 1; off < 16; off <<= 1)
            l_lane[r] += __shfl_xor(l_lane[r], off, 64);
    }
#pragma unroll
    for (int r = 0; r < 4; ++r) {
        int gi = i0 + wave * 16 + quad * 4 + r;
        float inv = 1.0f / l_lane[r];
#pragma unroll
        for (int s = 0; s < 4; ++s)
            attn_h[((size_t)(b * N_ + gi)) * C_ + h * HD + s * 16 + l16] =
                (_Float16)(o_acc[s][r] * inv);
    }
}

// ---------------------------------------------------------------------------
extern "C" void kernel_launch(void* const* d_in, const int* in_sizes, int n_in,
                              void* d_out, int out_size, void* d_ws, size_t ws_size,
                              hipStream_t stream) {
    const float* x       = (const float*)d_in[0];
    const float* bias    = (const float*)d_in[1];
    const float* W_qkv   = (const float*)d_in[2];
    const float* b_qkv   = (const float*)d_in[3];
    const float* q_scale = (const float*)d_in[4];
    const float* k_scale = (const float*)d_in[5];
    const float* W_proj  = (const float*)d_in[6];
    const float* b_proj  = (const float*)d_in[7];
    float* out = (float*)d_out;

    // ws layout (fp16 buffers):
    //   0     xh (8MB) | 8MB Wqkvt (6MB) | 16MB qh (8MB) | 24MB kh (8MB)
    //   32MB  vh (8MB) | 40MB vth (8MB)  | 48MB attn_h (8MB) | 56MB Wprojt (2MB)
    char* ws = (char*)d_ws;
    const size_t MB = 1024 * 1024;
    _Float16* xh     = (_Float16*)(ws);
    _Float16* Wqkvt  = (_Float16*)(ws + 8 * MB);
    _Float16* qh     = (_Float16*)(ws + 16 * MB);
    _Float16* kh     = (_Float16*)(ws + 24 * MB);
    _Float16* vh     = (_Float16*)(ws + 32 * MB);
    _Float16* vth    = (_Float16*)(ws + 40 * MB);
    _Float16* attn_h = (_Float16*)(ws + 48 * MB);
    _Float16* Wprojt = (_Float16*)(ws + 56 * MB);

    // 1) fused preprocessing: cast x, transpose+cast W_qkv and W_proj (one node)
    prep<<<4096 + 768 + 256, 256, 0, stream>>>(x, xh, W_qkv, Wqkvt, W_proj, Wprojt);
    // 2) qkv GEMM with fused rmsnorm/cast/layout epilogue
    gemm_qkv<<<dim3(K3 / 128, M_ / 128), 256, 0, stream>>>(xh, Wqkvt, b_qkv, q_scale, k_scale,
                                                           qh, kh, vh);
    // 3) per-head V transpose (fp16 -> fp16)
    v_transpose_h<<<dim3(N_ / 64, BH), 256, 0, stream>>>(vh, vth);
    // 4) fused attention: 128 q-rows/block, 512 threads
    flash_attn<<<dim3(N_ / 128, BH), 512, 0, stream>>>(qh, kh, vth, bias, attn_h);
    // 5) out = attn_h @ W_proj + b_proj (128x64 tiles, 2 blocks/CU)
    gemm_proj<<<dim3(C_ / 64, M_ / 128), 256, 0, stream>>>(attn_h, Wprojt, b_proj, out);
}